// Round 5
// baseline (990.435 us; speedup 1.0000x reference)
//
#include <hip/hip_runtime.h>
#include <math.h>

#define BDIM 8
#define FR   257
#define TT   300
#define CC   64
#define NN   (BDIM*TT)      // 2400
#define CPPC 16
#define GG   8
#define CPG  8              // CC/GG
#define KW   3
#define EPSV 1e-5f

#define FT    36            // inner rows per F-tile (LDS 19240 B -> 8 blocks/CU = 100% occ cap)
#define NTIL  8             // ceil(257/36) = 8 (covers 288 rows)
#define ROWS  38            // FT + 2 halo
#define FSTR  65            // LDS row stride: odd -> lane-indexed row reads conflict-free
#define NIT   10            // ceil(ROWS/4) wave-iterations

#define X1_ELEMS ((size_t)NN*FR*CC)     // 39,475,200
#define HP_ELEMS ((size_t)CPPC*NN*FR)   //  9,868,800

// ---------------- cross-lane helpers: VALU (DPP) instead of LDS-pipe ----------------
// update_dpp(old=0, bound_ctrl=true): invalid source lanes contribute 0 -> safe for sums.
template<int CTRL>
__device__ __forceinline__ float dpp_term(float v) {
    return __int_as_float(
        __builtin_amdgcn_update_dpp(0, __float_as_int(v), CTRL, 0xf, 0xf, true));
}
template<int PAT>
__device__ __forceinline__ float swz_term(float v) {
    return __int_as_float(__builtin_amdgcn_ds_swizzle(__float_as_int(v), PAT));
}

// Full wave-64 sum, all on the VALU pipe.
__device__ __forceinline__ float wave_sum64(float v) {
    v += dpp_term<0x111>(v);   // row_shr:1
    v += dpp_term<0x112>(v);   // row_shr:2
    v += dpp_term<0x114>(v);   // row_shr:4
    v += dpp_term<0x118>(v);   // row_shr:8
    v += dpp_term<0x142>(v);   // row_bcast:15
    v += dpp_term<0x143>(v);   // row_bcast:31
    return __int_as_float(__builtin_amdgcn_readlane(__float_as_int(v), 63));
}

__device__ __forceinline__ void ln_stats_dpp(float v, float& m, float& r) {
    float s  = wave_sum64(v);
    float ss = wave_sum64(v*v);
    m = s * (1.0f/64.0f);
    float var = ss * (1.0f/64.0f) - m*m;
    r = rsqrtf(var + EPSV);
}

// Grouped conv (G=8, K=3) via per-lane partials + xor-butterfly gather.
__device__ __forceinline__ float conv_row(float y0, float y1, float y2,
                                          const float wq[8][KW]) {
    float q[8];
    #pragma unroll
    for (int d = 0; d < 8; ++d)
        q[d] = y0*wq[d][0] + y1*wq[d][1] + y2*wq[d][2];
    float acc = q[0];
    acc += dpp_term<0xB1>(q[1]);    // quad_perm xor1
    acc += dpp_term<0x4E>(q[2]);    // quad_perm xor2
    acc += dpp_term<0x1B>(q[3]);    // quad_perm xor3
    acc += swz_term<0x101F>(q[4]);  // ds_swizzle xor4
    acc += swz_term<0x141F>(q[5]);  // ds_swizzle xor5
    acc += swz_term<0x181F>(q[6]);  // ds_swizzle xor6
    acc += dpp_term<0x141>(q[7]);   // row_half_mirror = xor7
    return acc;
}

// ---------------- Kernel 1: LN1 + conv1 + PReLU + res + LN2 + reduce + silu ----------------
// Round-2 phase structure; FT=36 + inner-only xs -> 8 blocks/CU. VGPR audit: natural
// allocation 52 <= 64-cap from (256,8) -> no spill.
__global__ __launch_bounds__(256, 8)
void k_fc1(const float* __restrict__ h,
           const float* __restrict__ g1, const float* __restrict__ b1,
           const float* __restrict__ w1, const float* __restrict__ cb1,
           const float* __restrict__ a1,
           const float* __restrict__ g2, const float* __restrict__ b2,
           const float* __restrict__ redw, const float* __restrict__ redb,
           float* __restrict__ x1, float* __restrict__ hpT)
{
    __shared__ float ys[ROWS*FSTR];   // normalized row state (halo incl)
    __shared__ float xs[FT*FSTR];     // residual row state (inner rows only)

    const int n  = blockIdx.x;
    const int f0 = blockIdx.y * FT;
    const int nf = min(FT, FR - f0);
    const int b = n / TT, t = n - b*TT;
    const int tid = threadIdx.x;
    const int lane = tid & 63, wid = tid >> 6;

    const float alpha = a1[0];
    const float gA = g1[lane], bA = b1[lane];
    const float gB = g2[lane], bB = b2[lane];
    const float cbv = cb1[lane];

    // Phase A: load h rows (with halo), LN1 via DPP -> ys; raw inner rows -> xs
    const size_t hb0 = ((size_t)b*FR*TT + t)*CC;
    #pragma unroll
    for (int it = 0; it < NIT; ++it) {
        int lr = wid + it*4;
        if (lr >= ROWS) continue;
        int f = f0 - 1 + lr;
        if (f >= 0 && f < FR) {
            float v = h[hb0 + (size_t)f*TT*CC + lane];
            if (lr >= 1 && lr <= nf) xs[(lr-1)*FSTR + lane] = v;
            float m, r; ln_stats_dpp(v, m, r);
            ys[lr*FSTR + lane] = (v - m) * r * gA + bA;
        } else {
            ys[lr*FSTR + lane] = 0.0f;
        }
    }
    __syncthreads();

    // conv weights loaded AFTER Phase A so wq's live range doesn't overlap LN work.
    const int l8 = lane & 7;
    const int gbase = lane & 56;
    float wq[8][KW];
    #pragma unroll
    for (int d = 0; d < 8; ++d) {
        const float* wp = w1 + (size_t)(gbase | (l8 ^ d))*(CPG*KW) + l8*KW;
        #pragma unroll
        for (int k = 0; k < KW; ++k) wq[d][k] = wp[k];
    }

    // Phase B: conv + butterfly + PReLU + residual; x2 -> xs, x1 -> global
    #pragma unroll
    for (int it = 0; it < NIT; ++it) {
        int lr = wid + it*4;
        if (lr < 1 || lr > nf) continue;
        float y0 = ys[(lr-1)*FSTR + lane];   // zero rows handle f-1<0 / f+1>=FR taps
        float y1 = ys[ lr   *FSTR + lane];
        float y2 = ys[(lr+1)*FSTR + lane];
        float acc = conv_row(y0, y1, y2, wq) + cbv;
        float pr = acc >= 0.0f ? acc : alpha*acc;
        float xv = xs[(lr-1)*FSTR + lane] + pr;   // same thread wrote this slot in Phase A
        xs[(lr-1)*FSTR + lane] = xv;
        int f = f0 + lr - 1;
        x1[(size_t)n*FR*CC + (size_t)f*CC + lane] = xv;
    }
    __syncthreads();   // all conv reads of LN1-ys complete before LN2 overwrites

    // Phase C: LN2 (DPP) -> ys
    #pragma unroll
    for (int it = 0; it < NIT; ++it) {
        int lr = wid + it*4;
        if (lr < 1 || lr > nf) continue;
        float v = xs[(lr-1)*FSTR + lane];
        float m, r; ln_stats_dpp(v, m, r);
        ys[lr*FSTR + lane] = (v - m) * r * gB + bB;
    }
    __syncthreads();

    // Phase D: reduce to CPP=16 + silu. lane = inner row, wave owns 4 p's.
    // ys reads stride-65 across lanes -> conflict-free; weights wave-uniform -> scalar loads.
    {
        const int L = lane;
        const int lr = (L < nf) ? (L + 1) : 1;
        const int p0 = wid * 4;
        const float* wp0 = redw + (size_t)(p0+0)*CC;
        const float* wp1 = redw + (size_t)(p0+1)*CC;
        const float* wp2 = redw + (size_t)(p0+2)*CC;
        const float* wp3 = redw + (size_t)(p0+3)*CC;
        float a0 = redb[p0+0], a1v = redb[p0+1], a2 = redb[p0+2], a3 = redb[p0+3];
        #pragma unroll 16
        for (int c = 0; c < CC; ++c) {
            float yv = ys[lr*FSTR + c];
            a0  += yv * wp0[c];
            a1v += yv * wp1[c];
            a2  += yv * wp2[c];
            a3  += yv * wp3[c];
        }
        if (L < nf) {
            int f = f0 + L;
            float s0 = a0  / (1.0f + expf(-a0));
            float s1 = a1v / (1.0f + expf(-a1v));
            float s2 = a2  / (1.0f + expf(-a2));
            float s3 = a3  / (1.0f + expf(-a3));
            size_t base = (size_t)n*FR + f;
            hpT[(size_t)(p0+0)*(NN*FR) + base] = s0;
            hpT[(size_t)(p0+1)*(NN*FR) + base] = s1;
            hpT[(size_t)(p0+2)*(NN*FR) + base] = s2;
            hpT[(size_t)(p0+3)*(NN*FR) + base] = s3;
        }
    }
}

// ---------------- Kernel 2: 16 batched GEMMs, 8x8 register tile ----------------
// (unchanged from Round 4 -- spill-free at (128,2); counters wanted next round)
#define GBM 128
#define GBN 64
#define GBK 16
#define GLDA 132   // 128 + 4 pad
#define GLDB 68

__global__ __launch_bounds__(128, 2)
void k_fgemm(const float* __restrict__ hpT, const float* __restrict__ fW,
             const float* __restrict__ fB, float* __restrict__ hp2T)
{
    __shared__ __align__(16) float As[GBK*GLDA];  // As[k][m]
    __shared__ __align__(16) float Bs[GBK*GLDB];  // Bs[k][j]
    const int c  = blockIdx.z;
    const int m0 = blockIdx.x * GBM;
    const int f0 = blockIdx.y * GBN;
    const int tid = threadIdx.x;
    const int tx = tid & 7;        // N dir, 8 cols of 8
    const int ty = tid >> 3;       // M dir, 16 rows of 8

    const float* Ab = hpT + (size_t)c*(NN*FR);
    const float* Bb = fW  + (size_t)c*(FR*FR);

    float acc[8][8];
    #pragma unroll
    for (int i = 0; i < 8; ++i)
        #pragma unroll
        for (int j = 0; j < 8; ++j) acc[i][j] = 0.0f;

    for (int k0 = 0; k0 < FR; k0 += GBK) {
        // stage A: 128 rows x 16 k; thread (m = e>>2, kq = e&3) loads float4, writes transposed
        #pragma unroll
        for (int l = 0; l < 4; ++l) {
            int e = tid + l*128;
            int m = e >> 2, kq = e & 3;
            int gm = m0 + m, gk = k0 + kq*4;
            float4 v = make_float4(0.f,0.f,0.f,0.f);
            if (gm < NN) {
                if (gk + 3 < FR) {
                    v = *reinterpret_cast<const float4*>(&Ab[(size_t)gm*FR + gk]);
                } else {
                    float tv[4] = {0.f,0.f,0.f,0.f};
                    #pragma unroll
                    for (int j = 0; j < 4; ++j) if (gk+j < FR) tv[j] = Ab[(size_t)gm*FR + gk + j];
                    v = make_float4(tv[0],tv[1],tv[2],tv[3]);
                }
            }
            As[(kq*4+0)*GLDA + m] = v.x;
            As[(kq*4+1)*GLDA + m] = v.y;
            As[(kq*4+2)*GLDA + m] = v.z;
            As[(kq*4+3)*GLDA + m] = v.w;
        }
        // stage B: 64 rows x 16 k
        #pragma unroll
        for (int l = 0; l < 2; ++l) {
            int e = tid + l*128;
            int j = e >> 2, kq = e & 3;
            int gf = f0 + j, gk = k0 + kq*4;
            float4 v = make_float4(0.f,0.f,0.f,0.f);
            if (gf < FR) {
                if (gk + 3 < FR) {
                    v = *reinterpret_cast<const float4*>(&Bb[(size_t)gf*FR + gk]);
                } else {
                    float tv[4] = {0.f,0.f,0.f,0.f};
                    #pragma unroll
                    for (int jj = 0; jj < 4; ++jj) if (gk+jj < FR) tv[jj] = Bb[(size_t)gf*FR + gk + jj];
                    v = make_float4(tv[0],tv[1],tv[2],tv[3]);
                }
            }
            Bs[(kq*4+0)*GLDB + j] = v.x;
            Bs[(kq*4+1)*GLDB + j] = v.y;
            Bs[(kq*4+2)*GLDB + j] = v.z;
            Bs[(kq*4+3)*GLDB + j] = v.w;
        }
        __syncthreads();

        #pragma unroll
        for (int k = 0; k < GBK; ++k) {
            const float4 a0 = *reinterpret_cast<const float4*>(&As[k*GLDA + ty*8]);
            const float4 a1 = *reinterpret_cast<const float4*>(&As[k*GLDA + ty*8 + 4]);
            const float4 b0 = *reinterpret_cast<const float4*>(&Bs[k*GLDB + tx*8]);
            const float4 b1 = *reinterpret_cast<const float4*>(&Bs[k*GLDB + tx*8 + 4]);
            const float av[8] = {a0.x,a0.y,a0.z,a0.w,a1.x,a1.y,a1.z,a1.w};
            const float bv[8] = {b0.x,b0.y,b0.z,b0.w,b1.x,b1.y,b1.z,b1.w};
            #pragma unroll
            for (int i = 0; i < 8; ++i)
                #pragma unroll
                for (int j = 0; j < 8; ++j)
                    acc[i][j] += av[i]*bv[j];
        }
        __syncthreads();
    }

    #pragma unroll
    for (int i = 0; i < 8; ++i) {
        int m = m0 + ty*8 + i;
        if (m >= NN) continue;
        #pragma unroll
        for (int j = 0; j < 8; ++j) {
            int fr = f0 + tx*8 + j;
            if (fr < FR)
                hp2T[(size_t)c*(NN*FR) + (size_t)m*FR + fr] = acc[i][j] + fB[c*FR + fr];
        }
    }
}

// ---------------- Kernel 3: expand + silu + residual + LN3 + conv2 ----------------
// Same FT=36 / inner-only-xs / (256,8) treatment.
__global__ __launch_bounds__(256, 8)
void k_fc2(const float* __restrict__ x1, const float* __restrict__ hp2T,
           const float* __restrict__ expw, const float* __restrict__ expb,
           const float* __restrict__ g3, const float* __restrict__ b3,
           const float* __restrict__ w2, const float* __restrict__ cb2,
           const float* __restrict__ a2,
           float* __restrict__ out)
{
    __shared__ float ys[ROWS*FSTR];
    __shared__ float xs[FT*FSTR];     // inner rows only

    const int n  = blockIdx.x;
    const int f0 = blockIdx.y * FT;
    const int nf = min(FT, FR - f0);
    const int b = n / TT, t = n - b*TT;
    const int tid = threadIdx.x;
    const int lane = tid & 63, wid = tid >> 6;

    const float ebv = expb[lane];
    const float gC = g3[lane], bC = b3[lane];
    const float alpha = a2[0];
    const float cbv = cb2[lane];

    // expand weights: live only during Phase A (wq loaded after)
    float ew[CPPC];
    #pragma unroll
    for (int p = 0; p < CPPC; ++p) ew[p] = expw[lane*CPPC + p];

    // Phase A: x2 = x1 + silu(expand(hp2)) for all rows; LN3 (DPP) -> ys; inner raw -> xs
    #pragma unroll
    for (int it = 0; it < NIT; ++it) {
        int lr = wid + it*4;
        if (lr >= ROWS) continue;
        int f = f0 - 1 + lr;
        if (f >= 0 && f < FR) {
            size_t base = (size_t)n*FR + f;
            float z = ebv;
            #pragma unroll
            for (int p = 0; p < CPPC; ++p)
                z += hp2T[(size_t)p*(NN*FR) + base] * ew[p];
            float sg = z / (1.0f + expf(-z));
            float v = x1[(size_t)n*FR*CC + (size_t)f*CC + lane] + sg;
            if (lr >= 1 && lr <= nf) xs[(lr-1)*FSTR + lane] = v;
            float m, r; ln_stats_dpp(v, m, r);
            ys[lr*FSTR + lane] = (v - m) * r * gC + bC;
        } else {
            ys[lr*FSTR + lane] = 0.0f;
        }
    }
    __syncthreads();

    // conv weights AFTER Phase A: live range doesn't overlap ew
    const int l8 = lane & 7;
    const int gbase = lane & 56;
    float wq[8][KW];
    #pragma unroll
    for (int d = 0; d < 8; ++d) {
        const float* wp = w2 + (size_t)(gbase | (l8 ^ d))*(CPG*KW) + l8*KW;
        #pragma unroll
        for (int k = 0; k < KW; ++k) wq[d][k] = wp[k];
    }

    // Phase B: conv2 + PReLU + residual -> out in [B, FR, TT, CC]
    const size_t ob0 = ((size_t)b*FR*TT + t)*CC;
    #pragma unroll
    for (int it = 0; it < NIT; ++it) {
        int lr = wid + it*4;
        if (lr < 1 || lr > nf) continue;
        float y0 = ys[(lr-1)*FSTR + lane];
        float y1 = ys[ lr   *FSTR + lane];
        float y2 = ys[(lr+1)*FSTR + lane];
        float acc = conv_row(y0, y1, y2, wq) + cbv;
        float pr = acc >= 0.0f ? acc : alpha*acc;
        int f = f0 + lr - 1;
        out[ob0 + (size_t)f*TT*CC + lane] = xs[(lr-1)*FSTR + lane] + pr;
    }
}

extern "C" void kernel_launch(void* const* d_in, const int* in_sizes, int n_in,
                              void* d_out, int out_size, void* d_ws, size_t ws_size,
                              hipStream_t stream) {
    const float* h      = (const float*)d_in[0];
    const float* fc1_g  = (const float*)d_in[1];
    const float* fc1_b  = (const float*)d_in[2];
    const float* fc1_w  = (const float*)d_in[3];
    const float* fc1_cb = (const float*)d_in[4];
    const float* fc1_a  = (const float*)d_in[5];
    const float* fbl_g  = (const float*)d_in[6];
    const float* fbl_b  = (const float*)d_in[7];
    const float* red_w  = (const float*)d_in[8];
    const float* red_b  = (const float*)d_in[9];
    const float* fW     = (const float*)d_in[10];
    const float* fB     = (const float*)d_in[11];
    const float* exp_w  = (const float*)d_in[12];
    const float* exp_b  = (const float*)d_in[13];
    const float* fc2_g  = (const float*)d_in[14];
    const float* fc2_b  = (const float*)d_in[15];
    const float* fc2_w  = (const float*)d_in[16];
    const float* fc2_cb = (const float*)d_in[17];
    const float* fc2_a  = (const float*)d_in[18];

    float* ws   = (float*)d_ws;
    float* x1   = ws;
    float* hpT  = x1 + X1_ELEMS;
    float* hp2T = hpT + HP_ELEMS;

    dim3 g1(NN, NTIL);
    k_fc1<<<g1, 256, 0, stream>>>(h, fc1_g, fc1_b, fc1_w, fc1_cb, fc1_a,
                                  fbl_g, fbl_b, red_w, red_b, x1, hpT);

    dim3 g2((NN + GBM - 1)/GBM, (FR + GBN - 1)/GBN, CPPC);
    k_fgemm<<<g2, 128, 0, stream>>>(hpT, fW, fB, hp2T);

    dim3 g3(NN, NTIL);
    k_fc2<<<g3, 256, 0, stream>>>(x1, hp2T, exp_w, exp_b,
                                  fc2_g, fc2_b, fc2_w, fc2_cb, fc2_a,
                                  (float*)d_out);
}

// Round 6
// 883.458 us; speedup vs baseline: 1.1211x; 1.1211x over previous
//
#include <hip/hip_runtime.h>
#include <math.h>

#define BDIM 8
#define FR   257
#define TT   300
#define CC   64
#define NN   (BDIM*TT)      // 2400
#define CPPC 16
#define GG   8
#define CPG  8              // CC/GG
#define KW   3
#define EPSV 1e-5f

#define FT    64            // inner rows per F-tile (Phase D: all 64 lanes useful)
#define NTIL  5             // ceil(257/64)
#define ROWS  66            // FT + 2 halo
#define FSTR  65            // LDS row stride: odd -> lane-channel & row-per-lane reads conflict-free

#define X1_ELEMS ((size_t)NN*FR*CC)     // 39,475,200
#define HP_ELEMS ((size_t)CPPC*NN*FR)   //  9,868,800

// ---------------- cross-lane helpers ----------------
template<int CTRL>
__device__ __forceinline__ float dpp_term(float v) {
    return __int_as_float(
        __builtin_amdgcn_update_dpp(0, __float_as_int(v), CTRL, 0xf, 0xf, true));
}
template<int PAT>
__device__ __forceinline__ float swz_term(float v) {
    return __int_as_float(__builtin_amdgcn_ds_swizzle(__float_as_int(v), PAT));
}

// Per-32-lane-half LN stats: each half-wave holds ONE row, lane owns 2 channels (v.x,v.y).
// Reduce within the half: row_shr 1/2/4/8 + row_bcast15 -> lane31 (lane63) = half-sum;
// ds_swizzle or=31 (0x03E0) broadcasts lane31 within lanes0-31 and lane63 within 32-63.
__device__ __forceinline__ void ln_stats_pair(float2 v, float& m, float& r) {
    float s  = v.x + v.y;
    float ss = v.x*v.x + v.y*v.y;
    s += dpp_term<0x111>(s);  ss += dpp_term<0x111>(ss);   // row_shr:1
    s += dpp_term<0x112>(s);  ss += dpp_term<0x112>(ss);   // row_shr:2
    s += dpp_term<0x114>(s);  ss += dpp_term<0x114>(ss);   // row_shr:4
    s += dpp_term<0x118>(s);  ss += dpp_term<0x118>(ss);   // row_shr:8
    s += dpp_term<0x142>(s);  ss += dpp_term<0x142>(ss);   // row_bcast:15 -> lane31/63 half-sums
    s  = swz_term<0x03E0>(s);                              // src lane 31 within each 32-group
    ss = swz_term<0x03E0>(ss);
    m = s * (1.0f/64.0f);
    float var = ss * (1.0f/64.0f) - m*m;
    r = rsqrtf(var + EPSV);
}

// Grouped conv (G=8, K=3) via per-lane partials + xor-butterfly gather (scalar lane=channel).
__device__ __forceinline__ float conv_row(float y0, float y1, float y2,
                                          const float wq[8][KW]) {
    float q[8];
    #pragma unroll
    for (int d = 0; d < 8; ++d)
        q[d] = y0*wq[d][0] + y1*wq[d][1] + y2*wq[d][2];
    float acc = q[0];
    acc += dpp_term<0xB1>(q[1]);    // quad_perm xor1
    acc += dpp_term<0x4E>(q[2]);    // quad_perm xor2
    acc += dpp_term<0x1B>(q[3]);    // quad_perm xor3
    acc += swz_term<0x101F>(q[4]);  // ds_swizzle xor4
    acc += swz_term<0x141F>(q[5]);  // ds_swizzle xor5
    acc += swz_term<0x181F>(q[6]);  // ds_swizzle xor6
    acc += dpp_term<0x141>(q[7]);   // row_half_mirror = xor7
    return acc;
}

// LDS dword-pair helpers (FSTR odd -> can't use b64; adjacent b32 pairs merge to ds_*2_b32)
__device__ __forceinline__ void lds_wr2(float* p, int idx, float2 v) {
    p[idx] = v.x; p[idx+1] = v.y;
}
__device__ __forceinline__ float2 lds_rd2(const float* p, int idx) {
    return make_float2(p[idx], p[idx+1]);
}

// ---------------- Kernel 1: LN1 + conv1 + PReLU + res + LN2 + reduce + silu ----------------
// Phases A/C vectorized: half-wave = row, lane = channel pair. Phases B/D scalar (proven).
__global__ __launch_bounds__(256, 2)
void k_fc1(const float* __restrict__ h,
           const float* __restrict__ g1, const float* __restrict__ b1,
           const float* __restrict__ w1, const float* __restrict__ cb1,
           const float* __restrict__ a1,
           const float* __restrict__ g2, const float* __restrict__ b2,
           const float* __restrict__ redw, const float* __restrict__ redb,
           float* __restrict__ x1, float* __restrict__ hpT)
{
    __shared__ float ys[ROWS*FSTR];   // normalized row state (halo incl)
    __shared__ float xs[FT*FSTR];     // residual row state (inner rows only)

    const int n  = blockIdx.x;
    const int f0 = blockIdx.y * FT;
    const int nf = min(FT, FR - f0);
    const int b = n / TT, t = n - b*TT;
    const int tid = threadIdx.x;
    const int lane = tid & 63, wid = tid >> 6;
    const int hl = lane & 31, half = lane >> 5;
    const int ch = hl << 1;           // channel pair base for float2 phases

    const float2 gA2 = *reinterpret_cast<const float2*>(&g1[ch]);
    const float2 bA2 = *reinterpret_cast<const float2*>(&b1[ch]);

    // Phase A: load h row pairs (halo incl), LN1 -> ys; raw inner rows -> xs
    const size_t hb0 = ((size_t)b*FR*TT + t)*CC;
    #pragma unroll
    for (int it = 0; it < 9; ++it) {
        int rp = wid + it*4;
        if (rp >= 33) continue;
        int lr = 2*rp + half;         // row 0..65, one per half-wave
        int f = f0 - 1 + lr;
        if (f >= 0 && f < FR) {
            float2 v = *reinterpret_cast<const float2*>(&h[hb0 + (size_t)f*TT*CC + ch]);
            if (lr >= 1 && lr <= nf) lds_wr2(xs, (lr-1)*FSTR + ch, v);
            float m, r; ln_stats_pair(v, m, r);
            float2 o = make_float2((v.x - m)*r*gA2.x + bA2.x,
                                   (v.y - m)*r*gA2.y + bA2.y);
            lds_wr2(ys, lr*FSTR + ch, o);
        } else {
            lds_wr2(ys, lr*FSTR + ch, make_float2(0.f, 0.f));
        }
    }
    __syncthreads();

    // conv weights loaded after Phase A (short live range)
    const int l8 = lane & 7;
    const int gbase = lane & 56;
    float wq[8][KW];
    #pragma unroll
    for (int d = 0; d < 8; ++d) {
        const float* wp = w1 + (size_t)(gbase | (l8 ^ d))*(CPG*KW) + l8*KW;
        #pragma unroll
        for (int k = 0; k < KW; ++k) wq[d][k] = wp[k];
    }
    const float alpha = a1[0];
    const float cbv = cb1[lane];

    // Phase B (scalar, lane=channel): conv + butterfly + PReLU + residual; x2 -> xs, x1 -> global
    #pragma unroll
    for (int it = 0; it < 17; ++it) {
        int lr = wid + it*4;
        if (lr < 1 || lr > nf) continue;
        float y0 = ys[(lr-1)*FSTR + lane];   // zero rows handle f-1<0 / f+1>=FR taps
        float y1 = ys[ lr   *FSTR + lane];
        float y2 = ys[(lr+1)*FSTR + lane];
        float acc = conv_row(y0, y1, y2, wq) + cbv;
        float pr = acc >= 0.0f ? acc : alpha*acc;
        float xv = xs[(lr-1)*FSTR + lane] + pr;
        xs[(lr-1)*FSTR + lane] = xv;
        int f = f0 + lr - 1;
        x1[(size_t)n*FR*CC + (size_t)f*CC + lane] = xv;
    }
    __syncthreads();   // conv reads of ys done; B's xs writes visible

    // Phase C (pairs): LN2 on inner rows -> ys
    const float2 gB2 = *reinterpret_cast<const float2*>(&g2[ch]);
    const float2 bB2 = *reinterpret_cast<const float2*>(&b2[ch]);
    #pragma unroll
    for (int it = 0; it < 8; ++it) {
        int rp = wid + it*4;          // rp < 32 always
        int ir = 2*rp + half;         // inner row 0..63
        if (ir >= nf) continue;
        float2 v = lds_rd2(xs, ir*FSTR + ch);
        float m, r; ln_stats_pair(v, m, r);
        float2 o = make_float2((v.x - m)*r*gB2.x + bB2.x,
                               (v.y - m)*r*gB2.y + bB2.y);
        lds_wr2(ys, (ir+1)*FSTR + ch, o);
    }
    __syncthreads();

    // Phase D (scalar): reduce to CPP=16 + silu. lane = inner row, wave owns 4 p's.
    // ys reads stride-65 -> conflict-free; weights wave-uniform -> scalar loads.
    {
        const int L = lane;
        const int lr = (L < nf) ? (L + 1) : 1;
        const int p0 = wid * 4;
        const float* wp0 = redw + (size_t)(p0+0)*CC;
        const float* wp1 = redw + (size_t)(p0+1)*CC;
        const float* wp2 = redw + (size_t)(p0+2)*CC;
        const float* wp3 = redw + (size_t)(p0+3)*CC;
        float a0 = redb[p0+0], a1v = redb[p0+1], a2 = redb[p0+2], a3 = redb[p0+3];
        #pragma unroll 16
        for (int c = 0; c < CC; ++c) {
            float yv = ys[lr*FSTR + c];
            a0  += yv * wp0[c];
            a1v += yv * wp1[c];
            a2  += yv * wp2[c];
            a3  += yv * wp3[c];
        }
        if (L < nf) {
            int f = f0 + L;
            float s0 = a0  / (1.0f + expf(-a0));
            float s1 = a1v / (1.0f + expf(-a1v));
            float s2 = a2  / (1.0f + expf(-a2));
            float s3 = a3  / (1.0f + expf(-a3));
            size_t base = (size_t)n*FR + f;
            hpT[(size_t)(p0+0)*(NN*FR) + base] = s0;
            hpT[(size_t)(p0+1)*(NN*FR) + base] = s1;
            hpT[(size_t)(p0+2)*(NN*FR) + base] = s2;
            hpT[(size_t)(p0+3)*(NN*FR) + base] = s3;
        }
    }
}

// ---------------- Kernel 2: 16 batched GEMMs, 8x8 register tile ----------------
// (unchanged from Round 4 -- spill-free at (128,2))
#define GBM 128
#define GBN 64
#define GBK 16
#define GLDA 132   // 128 + 4 pad
#define GLDB 68

__global__ __launch_bounds__(128, 2)
void k_fgemm(const float* __restrict__ hpT, const float* __restrict__ fW,
             const float* __restrict__ fB, float* __restrict__ hp2T)
{
    __shared__ __align__(16) float As[GBK*GLDA];  // As[k][m]
    __shared__ __align__(16) float Bs[GBK*GLDB];  // Bs[k][j]
    const int c  = blockIdx.z;
    const int m0 = blockIdx.x * GBM;
    const int f0 = blockIdx.y * GBN;
    const int tid = threadIdx.x;
    const int tx = tid & 7;        // N dir
    const int ty = tid >> 3;       // M dir

    const float* Ab = hpT + (size_t)c*(NN*FR);
    const float* Bb = fW  + (size_t)c*(FR*FR);

    float acc[8][8];
    #pragma unroll
    for (int i = 0; i < 8; ++i)
        #pragma unroll
        for (int j = 0; j < 8; ++j) acc[i][j] = 0.0f;

    for (int k0 = 0; k0 < FR; k0 += GBK) {
        #pragma unroll
        for (int l = 0; l < 4; ++l) {
            int e = tid + l*128;
            int m = e >> 2, kq = e & 3;
            int gm = m0 + m, gk = k0 + kq*4;
            float4 v = make_float4(0.f,0.f,0.f,0.f);
            if (gm < NN) {
                if (gk + 3 < FR) {
                    v = *reinterpret_cast<const float4*>(&Ab[(size_t)gm*FR + gk]);
                } else {
                    float tv[4] = {0.f,0.f,0.f,0.f};
                    #pragma unroll
                    for (int j = 0; j < 4; ++j) if (gk+j < FR) tv[j] = Ab[(size_t)gm*FR + gk + j];
                    v = make_float4(tv[0],tv[1],tv[2],tv[3]);
                }
            }
            As[(kq*4+0)*GLDA + m] = v.x;
            As[(kq*4+1)*GLDA + m] = v.y;
            As[(kq*4+2)*GLDA + m] = v.z;
            As[(kq*4+3)*GLDA + m] = v.w;
        }
        #pragma unroll
        for (int l = 0; l < 2; ++l) {
            int e = tid + l*128;
            int j = e >> 2, kq = e & 3;
            int gf = f0 + j, gk = k0 + kq*4;
            float4 v = make_float4(0.f,0.f,0.f,0.f);
            if (gf < FR) {
                if (gk + 3 < FR) {
                    v = *reinterpret_cast<const float4*>(&Bb[(size_t)gf*FR + gk]);
                } else {
                    float tv[4] = {0.f,0.f,0.f,0.f};
                    #pragma unroll
                    for (int jj = 0; jj < 4; ++jj) if (gk+jj < FR) tv[jj] = Bb[(size_t)gf*FR + gk + jj];
                    v = make_float4(tv[0],tv[1],tv[2],tv[3]);
                }
            }
            Bs[(kq*4+0)*GLDB + j] = v.x;
            Bs[(kq*4+1)*GLDB + j] = v.y;
            Bs[(kq*4+2)*GLDB + j] = v.z;
            Bs[(kq*4+3)*GLDB + j] = v.w;
        }
        __syncthreads();

        #pragma unroll
        for (int k = 0; k < GBK; ++k) {
            const float4 a0 = *reinterpret_cast<const float4*>(&As[k*GLDA + ty*8]);
            const float4 a1 = *reinterpret_cast<const float4*>(&As[k*GLDA + ty*8 + 4]);
            const float4 b0 = *reinterpret_cast<const float4*>(&Bs[k*GLDB + tx*8]);
            const float4 b1 = *reinterpret_cast<const float4*>(&Bs[k*GLDB + tx*8 + 4]);
            const float av[8] = {a0.x,a0.y,a0.z,a0.w,a1.x,a1.y,a1.z,a1.w};
            const float bv[8] = {b0.x,b0.y,b0.z,b0.w,b1.x,b1.y,b1.z,b1.w};
            #pragma unroll
            for (int i = 0; i < 8; ++i)
                #pragma unroll
                for (int j = 0; j < 8; ++j)
                    acc[i][j] += av[i]*bv[j];
        }
        __syncthreads();
    }

    #pragma unroll
    for (int i = 0; i < 8; ++i) {
        int m = m0 + ty*8 + i;
        if (m >= NN) continue;
        #pragma unroll
        for (int j = 0; j < 8; ++j) {
            int fr = f0 + tx*8 + j;
            if (fr < FR)
                hp2T[(size_t)c*(NN*FR) + (size_t)m*FR + fr] = acc[i][j] + fB[c*FR + fr];
        }
    }
}

// ---------------- Kernel 3: expand + silu + residual + LN3 + conv2 ----------------
// Phase A vectorized (pairs); Phase B scalar conv (proven).
__global__ __launch_bounds__(256, 2)
void k_fc2(const float* __restrict__ x1, const float* __restrict__ hp2T,
           const float* __restrict__ expw, const float* __restrict__ expb,
           const float* __restrict__ g3, const float* __restrict__ b3,
           const float* __restrict__ w2, const float* __restrict__ cb2,
           const float* __restrict__ a2,
           float* __restrict__ out)
{
    __shared__ float ys[ROWS*FSTR];
    __shared__ float xs[FT*FSTR];     // inner rows only

    const int n  = blockIdx.x;
    const int f0 = blockIdx.y * FT;
    const int nf = min(FT, FR - f0);
    const int b = n / TT, t = n - b*TT;
    const int tid = threadIdx.x;
    const int lane = tid & 63, wid = tid >> 6;
    const int hl = lane & 31, half = lane >> 5;
    const int ch = hl << 1;

    const float2 gC2 = *reinterpret_cast<const float2*>(&g3[ch]);
    const float2 bC2 = *reinterpret_cast<const float2*>(&b3[ch]);
    const float2 eb2 = *reinterpret_cast<const float2*>(&expb[ch]);

    // expand weights for the channel pair: ew2[p] = (expw[ch][p], expw[ch+1][p])
    float2 ew2[CPPC];
    #pragma unroll
    for (int p = 0; p < CPPC; ++p)
        ew2[p] = make_float2(expw[ch*CPPC + p], expw[(ch+1)*CPPC + p]);

    // Phase A (pairs): x2 = x1 + silu(expand(hp2)); LN3 -> ys; inner raw -> xs
    #pragma unroll
    for (int it = 0; it < 9; ++it) {
        int rp = wid + it*4;
        if (rp >= 33) continue;
        int lr = 2*rp + half;
        int f = f0 - 1 + lr;
        if (f >= 0 && f < FR) {
            size_t base = (size_t)n*FR + f;
            float2 z = eb2;
            #pragma unroll
            for (int p = 0; p < CPPC; ++p) {
                float hp = hp2T[(size_t)p*(NN*FR) + base];   // uniform per half-wave
                z.x += hp * ew2[p].x;
                z.y += hp * ew2[p].y;
            }
            float2 sg = make_float2(z.x / (1.0f + expf(-z.x)),
                                    z.y / (1.0f + expf(-z.y)));
            float2 xv = *reinterpret_cast<const float2*>(&x1[(size_t)n*FR*CC + (size_t)f*CC + ch]);
            float2 v = make_float2(xv.x + sg.x, xv.y + sg.y);
            if (lr >= 1 && lr <= nf) lds_wr2(xs, (lr-1)*FSTR + ch, v);
            float m, r; ln_stats_pair(v, m, r);
            float2 o = make_float2((v.x - m)*r*gC2.x + bC2.x,
                                   (v.y - m)*r*gC2.y + bC2.y);
            lds_wr2(ys, lr*FSTR + ch, o);
        } else {
            lds_wr2(ys, lr*FSTR + ch, make_float2(0.f, 0.f));
        }
    }
    __syncthreads();

    // conv weights after Phase A (ew2 dead by here)
    const int l8 = lane & 7;
    const int gbase = lane & 56;
    float wq[8][KW];
    #pragma unroll
    for (int d = 0; d < 8; ++d) {
        const float* wp = w2 + (size_t)(gbase | (l8 ^ d))*(CPG*KW) + l8*KW;
        #pragma unroll
        for (int k = 0; k < KW; ++k) wq[d][k] = wp[k];
    }
    const float alpha = a2[0];
    const float cbv = cb2[lane];

    // Phase B (scalar): conv2 + PReLU + residual -> out in [B, FR, TT, CC]
    const size_t ob0 = ((size_t)b*FR*TT + t)*CC;
    #pragma unroll
    for (int it = 0; it < 17; ++it) {
        int lr = wid + it*4;
        if (lr < 1 || lr > nf) continue;
        float y0 = ys[(lr-1)*FSTR + lane];
        float y1 = ys[ lr   *FSTR + lane];
        float y2 = ys[(lr+1)*FSTR + lane];
        float acc = conv_row(y0, y1, y2, wq) + cbv;
        float pr = acc >= 0.0f ? acc : alpha*acc;
        int f = f0 + lr - 1;
        out[ob0 + (size_t)f*TT*CC + lane] = xs[(lr-1)*FSTR + lane] + pr;
    }
}

extern "C" void kernel_launch(void* const* d_in, const int* in_sizes, int n_in,
                              void* d_out, int out_size, void* d_ws, size_t ws_size,
                              hipStream_t stream) {
    const float* h      = (const float*)d_in[0];
    const float* fc1_g  = (const float*)d_in[1];
    const float* fc1_b  = (const float*)d_in[2];
    const float* fc1_w  = (const float*)d_in[3];
    const float* fc1_cb = (const float*)d_in[4];
    const float* fc1_a  = (const float*)d_in[5];
    const float* fbl_g  = (const float*)d_in[6];
    const float* fbl_b  = (const float*)d_in[7];
    const float* red_w  = (const float*)d_in[8];
    const float* red_b  = (const float*)d_in[9];
    const float* fW     = (const float*)d_in[10];
    const float* fB     = (const float*)d_in[11];
    const float* exp_w  = (const float*)d_in[12];
    const float* exp_b  = (const float*)d_in[13];
    const float* fc2_g  = (const float*)d_in[14];
    const float* fc2_b  = (const float*)d_in[15];
    const float* fc2_w  = (const float*)d_in[16];
    const float* fc2_cb = (const float*)d_in[17];
    const float* fc2_a  = (const float*)d_in[18];

    float* ws   = (float*)d_ws;
    float* x1   = ws;
    float* hpT  = x1 + X1_ELEMS;
    float* hp2T = hpT + HP_ELEMS;

    dim3 g1(NN, NTIL);
    k_fc1<<<g1, 256, 0, stream>>>(h, fc1_g, fc1_b, fc1_w, fc1_cb, fc1_a,
                                  fbl_g, fbl_b, red_w, red_b, x1, hpT);

    dim3 g2((NN + GBM - 1)/GBM, (FR + GBN - 1)/GBN, CPPC);
    k_fgemm<<<g2, 128, 0, stream>>>(hpT, fW, fB, hp2T);

    dim3 g3(NN, NTIL);
    k_fc2<<<g3, 256, 0, stream>>>(x1, hp2T, exp_w, exp_b,
                                  fc2_g, fc2_b, fc2_w, fc2_cb, fc2_a,
                                  (float*)d_out);
}